// Round 3
// baseline (2082.236 us; speedup 1.0000x reference)
//
#include <hip/hip_runtime.h>
#include <stdint.h>

#define TOKENS 8192
#define IN_F   3072
#define OUT_F  8192
#define GROUP  128

// GEMM: 256x256 tile, BK=64, 8 waves (2M x 4N), 512 threads.
// R3: read-ahead pipeline. ds_reads issued in phase p feed MFMA of phase
// p+1, so MFMA never lgkm-stalls and the LDS port drains under the MFMA
// cluster. 4 phases/tile, ONE barrier per phase, lgkmcnt(0)+counted vmcnt
// before each barrier. Reads/phase: 4/8/4/8 (balanced). Stages/phase:
// 0/1/2/1 half-tiles of T+2, each placed >=1 boundary after the last read
// of that LDS region (write-after-read safe). vmcnt allowances per
// boundary derived from stream-retirement order: 8/4/6/10.
#define BM 256
#define BN 256
#define BK 64
#define NT (IN_F / BK)   // 48 K-tiles

typedef __bf16 bf16x8 __attribute__((ext_vector_type(8)));
typedef float  f32x4  __attribute__((ext_vector_type(4)));

// RNE float -> bf16 bits
__device__ __forceinline__ uint32_t f2bf(float f) {
    union { float f; uint32_t u; } v; v.f = f;
    uint32_t u = v.u;
    return (u + 0x7fffu + ((u >> 16) & 1u)) >> 16;
}

// async global -> LDS, 16 bytes per lane (global_load_lds_dwordx4)
__device__ __forceinline__ void async_cp16(const uint16_t* g, uint16_t* l) {
    __builtin_amdgcn_global_load_lds(
        (const __attribute__((address_space(1))) void*)g,
        (__attribute__((address_space(3))) void*)l,
        16, 0, 0);
}

// boundary: drain my ds_reads (issued this phase, consumed next phase) and
// retire stage-writes to vmcnt(N) BEFORE the barrier; after the barrier all
// waves' LDS writes/reads up to here are visible/complete.
#define BOUNDARY(N)                                                        \
    asm volatile("s_waitcnt vmcnt(" #N ") lgkmcnt(0)" ::: "memory");       \
    __builtin_amdgcn_s_barrier();                                          \
    asm volatile("" ::: "memory");

// one C-quadrant: 16 MFMA, ks-outer so acc-dependent pairs are 8 apart
#define MFMA_Q(Aset, Bset, ro, co)                                         \
    __builtin_amdgcn_s_setprio(1);                                         \
    _Pragma("unroll") for (int ks = 0; ks < 2; ++ks)                       \
    _Pragma("unroll") for (int i = 0; i < 4; ++i)                          \
    _Pragma("unroll") for (int j = 0; j < 2; ++j)                          \
        acc[(ro) + i][(co) + j] = __builtin_amdgcn_mfma_f32_16x16x32_bf16( \
            Aset[i][ks], Bset[j][ks], acc[(ro) + i][(co) + j], 0, 0, 0);   \
    __builtin_amdgcn_s_setprio(0);

// ---------------------------------------------------------------------------
// Prep (one launch): blocks [0,12288) dequant packed int4 -> bf16 W;
// blocks [12288,24576) convert x fp32 -> bf16.
// ---------------------------------------------------------------------------
__global__ __launch_bounds__(256) void prep(const int* __restrict__ packed,
                                            const float* __restrict__ scales,
                                            const float* __restrict__ x,
                                            uint16_t* __restrict__ W,
                                            uint16_t* __restrict__ xb) {
    if (blockIdx.x < 12288) {
        const int t   = blockIdx.x * 256 + threadIdx.x;
        const int idx = t * 4;                 // packed-element index
        const int row  = idx / (IN_F / 2);     // 1536 packed per row
        const int pcol = idx - row * (IN_F / 2);
        const int grp  = pcol >> 6;            // 64 packed = 128 cols per group
        const float s  = scales[row * (IN_F / GROUP) + grp];

        const int4 p = *(const int4*)(packed + idx);
        int vals[4] = {p.x, p.y, p.z, p.w};
        uint32_t w[4];
#pragma unroll
        for (int i = 0; i < 4; ++i) {
            int b  = vals[i] & 255;
            int lo = b & 15;        lo = (lo >= 8) ? lo - 16 : lo;
            int hi = (b >> 4) & 15; hi = (hi >= 8) ? hi - 16 : hi;
            uint32_t e = f2bf((float)lo * s);   // even column
            uint32_t o = f2bf((float)hi * s);   // odd column
            w[i] = e | (o << 16);
        }
        uint4 res = {w[0], w[1], w[2], w[3]};
        *(uint4*)(W + (size_t)idx * 2) = res;
    } else {
        const size_t idx = ((size_t)(blockIdx.x - 12288) * 256 + threadIdx.x) * 8;
        const float4 a = *(const float4*)(x + idx);
        const float4 b = *(const float4*)(x + idx + 4);
        uint32_t w0 = f2bf(a.x) | (f2bf(a.y) << 16);
        uint32_t w1 = f2bf(a.z) | (f2bf(a.w) << 16);
        uint32_t w2 = f2bf(b.x) | (f2bf(b.y) << 16);
        uint32_t w3 = f2bf(b.z) | (f2bf(b.w) << 16);
        uint4 res = {w0, w1, w2, w3};
        *(uint4*)(xb + idx) = res;
    }
}

// ---------------------------------------------------------------------------
// GEMM: C[M,N] = A[M,K] * B[N,K]^T + bias  (bf16 in, fp32 out)
// ---------------------------------------------------------------------------
__global__ __launch_bounds__(512, 2) void gemm_bt(const uint16_t* __restrict__ A,
                                                  const uint16_t* __restrict__ B,
                                                  const float* __restrict__ bias,
                                                  float* __restrict__ C) {
    constexpr int K = IN_F;
    constexpr int N = OUT_F;

    // [buf][0=A,1=B][half*8192 + row*64 + col], 128 KiB
    __shared__ __align__(16) uint16_t lds[2][2][BM * BK];

    const int t    = threadIdx.x;
    const int lane = t & 63;
    const int wave = t >> 6;

    // XCD-aware bijective swizzle: 1024 wgs, 128 consecutive tiles per XCD.
    const int wg  = blockIdx.x;
    const int swz = (wg & 7) * 128 + (wg >> 3);
    const int bx  = swz & 31;          // N tile index
    const int by  = swz >> 5;          // M tile index

    const int wm = (wave >> 2) * 128;  // wave M offset: 0 / 128
    const int wn = (wave & 3) * 64;    // wave N offset: 0/64/128/192

    const int fr = lane & 15;          // row within 16-tile
    const int qq = lane >> 4;          // k-chunk sub-index 0..3

    // staging: thread covers rows (t>>3)+{0,64} of a 128-row half, slot t&7
    const int r0 = t >> 3;                 // 0..63
    const int sx = (t & 7) ^ (r0 & 7);     // swizzled global 16B chunk

    f32x4 acc[8][4] = {};
    bf16x8 Aa[4][2], Ab[4][2], Bb[2][2], Bc0[2][2], Bc1[2][2];

    auto stage = [&](int Tt, int isB, int half) {
        const uint16_t* gb = isB ? B : A;
        const int rowBase  = (isB ? bx : by) * 256 + half * 128;
        uint16_t* ld = &lds[Tt & 1][isB][half * 8192];
        const int kc = Tt * BK + sx * 8;
#pragma unroll
        for (int p = 0; p < 2; ++p)
            async_cp16(gb + (size_t)(rowBase + r0 + 64 * p) * K + kc,
                       ld + 4096 * p + t * 8);
    };
    // A register half: h=0 -> wave rows 0..63 (i0-3), h=1 -> 64..127
    auto rdA = [&](int Tt, int half, bf16x8 (&dst)[4][2]) {
        const uint16_t* sA = lds[Tt & 1][0];
#pragma unroll
        for (int i = 0; i < 4; ++i)
#pragma unroll
            for (int ks = 0; ks < 2; ++ks) {
                const int row = wm + half * 64 + i * 16 + fr;
                dst[i][ks] = *(const bf16x8*)(sA + row * 64 +
                                              (((ks * 4 + qq) ^ (row & 7)) * 8));
            }
    };
    // B register pair: h=0 -> wave cols 0..31 (j0-1), h=1 -> 32..63 (j2-3)
    auto rdB = [&](int Tt, int half, bf16x8 (&dst)[2][2]) {
        const uint16_t* sB = lds[Tt & 1][1];
#pragma unroll
        for (int j = 0; j < 2; ++j)
#pragma unroll
            for (int ks = 0; ks < 2; ++ks) {
                const int row = wn + half * 32 + j * 16 + fr;
                dst[j][ks] = *(const bf16x8*)(sB + row * 64 +
                                              (((ks * 4 + qq) ^ (row & 7)) * 8));
            }
    };

    // prologue: stage tiles 0,1 in canonical stream order (B.h0,A.h0,B.h1,A.h1)
    stage(0, 1, 0); stage(0, 0, 0); stage(0, 1, 1); stage(0, 0, 1);
    stage(1, 1, 0); stage(1, 0, 0); stage(1, 1, 1); stage(1, 0, 1);
    asm volatile("s_waitcnt vmcnt(8)" ::: "memory");   // tile0 resident
    __builtin_amdgcn_s_barrier();
    asm volatile("" ::: "memory");
    rdB(0, 0, Bc0);          // B0(0)
    rdA(0, 0, Aa);           // A0(0)
    BOUNDARY(10);

    // tile body: MFMA consumes regs read one phase earlier.
    //   P0: MFMA A0xB0;            read B1(T)      [4]
    //   P1: MFMA A0xB1; stage Bh0; read A1(T)      [8]
    //   P2: MFMA A1xB1; stage Ah0,Bh1; read B0(T+1)[4]
    //   P3: MFMA A1xB0; stage Ah1; read A0(T+1)    [8]
    auto body = [&](int T, bf16x8 (&Bcur)[2][2], bf16x8 (&Bnext)[2][2]) {
        // ---- P0 ----
        rdB(T, 1, Bb);
        MFMA_Q(Aa, Bcur, 0, 0);
        BOUNDARY(8);
        // ---- P1 ----
        if (T + 2 < NT) stage(T + 2, 1, 0);
        rdA(T, 1, Ab);
        MFMA_Q(Aa, Bb, 0, 2);
        BOUNDARY(4);
        // ---- P2 ----
        if (T + 2 < NT) { stage(T + 2, 0, 0); stage(T + 2, 1, 1); }
        if (T + 1 < NT) rdB(T + 1, 0, Bnext);
        MFMA_Q(Ab, Bb, 4, 2);
        BOUNDARY(6);
        // ---- P3 ----
        if (T + 2 < NT) stage(T + 2, 0, 1);
        if (T + 1 < NT) rdA(T + 1, 0, Aa);
        MFMA_Q(Ab, Bcur, 4, 0);
        BOUNDARY(10);
    };

    for (int tp = 0; tp < NT; tp += 2) {
        body(tp,     Bc0, Bc1);
        body(tp + 1, Bc1, Bc0);
    }

    // --- epilogue: C/D layout col=lane&15, row=(lane>>4)*4+reg ---
    const int cr = (lane >> 4) * 4;
    const int cc = lane & 15;
#pragma unroll
    for (int j = 0; j < 4; ++j) {
        const int col = bx * BN + wn + j * 16 + cc;
        const float bv = bias[col];
#pragma unroll
        for (int i = 0; i < 8; ++i) {
            const size_t base = (size_t)(by * BM + wm + i * 16 + cr) * N + col;
#pragma unroll
            for (int r = 0; r < 4; ++r)
                C[base + (size_t)r * N] = acc[i][j][r] + bv;
        }
    }
}

extern "C" void kernel_launch(void* const* d_in, const int* in_sizes, int n_in,
                              void* d_out, int out_size, void* d_ws, size_t ws_size,
                              hipStream_t stream) {
    const float* x      = (const float*)d_in[0];   // [8192, 3072] fp32
    const int*   packed = (const int*)d_in[1];     // [8192, 1536] int32 (byte vals)
    const float* scales = (const float*)d_in[2];   // [8192, 24] fp32
    const float* bias   = (const float*)d_in[3];   // [8192] fp32
    float*       out    = (float*)d_out;           // [8192, 8192] fp32

    uint16_t* W  = (uint16_t*)d_ws;                                     // 50.3 MB bf16
    uint16_t* Xb = (uint16_t*)((char*)d_ws + (size_t)OUT_F * IN_F * 2); // 50.3 MB bf16

    prep<<<24576, 256, 0, stream>>>(packed, scales, x, W, Xb);

    gemm_bt<<<dim3(1024), 512, 0, stream>>>(Xb, W, bias, out);
}

// Round 6
// 738.115 us; speedup vs baseline: 2.8210x; 2.8210x over previous
//
#include <hip/hip_runtime.h>
#include <stdint.h>

#define TOKENS 8192
#define IN_F   3072
#define OUT_F  8192
#define GROUP  128

// GEMM: 256x256 tile, BK=64, 8 waves (2M x 4N), 512 threads.
// R6: read-ahead pipeline with REGISTER-SET-CONGRUENT staging units.
// (R4/R5 raced: staging halves [0..127]/[128..255] did not match register
// sets for wm=128 / wn>=128 waves.) Units:
//   UA0 = rows {0..63}u{128..191}, UA1 = {64..127}u{192..255}
//   VB0 = rows bit5==0,            VB1 = rows bit5==1
// -> EVERY wave's A0f reads only UA0, A1f->UA1, B0f->VB0, B1f->VB1.
// Reads: P0 B1f[4], P1 A1f[8], P2 A0f(next)[8], P3end B0f(next)[4].
// MFMA: P0 A0xB0, P1 A0xB1, P2 A1xB1, P3 A1xB0 (operands loaded 1 phase
// ahead; LDS port drains under MFMA). Stages of T+2: P1 {UA0,VB0},
// P2 {VB1}, P3 {UA1} -- each region's last reader lgkm-forced >=1 barrier
// before the stage (UA0,VB0 <- P0.LGKM(4); VB1 <- P1.LGKM(8);
// UA1 <- P2.LGKM(8)). All ENTRY vmcnt(8): every forced load was issued
// exactly 4 phases (~1 tile) earlier; steady state never drains.
// Tail: tile NT-2 ENTRYs (8,4,2,0); tile NT-1 all 0, L2=0.
#define BM 256
#define BN 256
#define BK 64
#define NT (IN_F / BK)   // 48 K-tiles

typedef __bf16 bf16x8 __attribute__((ext_vector_type(8)));
typedef float  f32x4  __attribute__((ext_vector_type(4)));

__device__ __forceinline__ uint32_t f2bf(float f) {
    union { float f; uint32_t u; } v; v.f = f;
    uint32_t u = v.u;
    return (u + 0x7fffu + ((u >> 16) & 1u)) >> 16;
}

__device__ __forceinline__ void async_cp16(const uint16_t* g, uint16_t* l) {
    __builtin_amdgcn_global_load_lds(
        (const __attribute__((address_space(1))) void*)g,
        (__attribute__((address_space(3))) void*)l,
        16, 0, 0);
}

// entry boundary: counted vmcnt, then barrier
#define ENTRY(VN)                                                          \
    asm volatile("s_waitcnt vmcnt(" #VN ")" ::: "memory");                 \
    __builtin_amdgcn_s_barrier();                                          \
    asm volatile("" ::: "memory");

// force prior-phase ds_reads complete, leave own in flight (rule #18 fence)
#define LGKM(N)                                                            \
    asm volatile("s_waitcnt lgkmcnt(" #N ")" ::: "memory");                \
    __builtin_amdgcn_sched_barrier(0);

#define EXITB                                                              \
    asm volatile("" ::: "memory");                                         \
    __builtin_amdgcn_s_barrier();                                          \
    asm volatile("" ::: "memory");

// one C-quadrant: 16 MFMA (4x2 frags x 2 ks)
#define MFMA_Q(Aset, Bset, ro, co)                                         \
    __builtin_amdgcn_s_setprio(1);                                         \
    _Pragma("unroll") for (int ks = 0; ks < 2; ++ks)                       \
    _Pragma("unroll") for (int i = 0; i < 4; ++i)                          \
    _Pragma("unroll") for (int j = 0; j < 2; ++j)                          \
        acc[(ro) + i][(co) + j] = __builtin_amdgcn_mfma_f32_16x16x32_bf16( \
            Aset[i][ks], Bset[j][ks], acc[(ro) + i][(co) + j], 0, 0, 0);   \
    __builtin_amdgcn_s_setprio(0);

// ds_read a 4x2 A-set / 2x2 B-set from lane-base pointers + immediates
#define RD_A(dst, PK0, PK1, HIMM)                                          \
    _Pragma("unroll") for (int i = 0; i < 4; ++i) {                        \
        dst[i][0] = *(const bf16x8*)((PK0) + (HIMM) + i * 1024);           \
        dst[i][1] = *(const bf16x8*)((PK1) + (HIMM) + i * 1024);           \
    }
#define RD_B(dst, PK0, PK1, HIMM)                                          \
    _Pragma("unroll") for (int j = 0; j < 2; ++j) {                        \
        dst[j][0] = *(const bf16x8*)((PK0) + (HIMM) + j * 1024);           \
        dst[j][1] = *(const bf16x8*)((PK1) + (HIMM) + j * 1024);           \
    }

// stage one unit (2 x global_load_lds_dwordx4 per thread, p stride 128 rows)
// A unit u: source row = u*64 + p*128 + r0        (base Ag includes r0)
// B unit v: source row = v*32 + p*128 + r0+(r0&32) (base Bg includes rB)
#define STAGE(Tt, ISB, UNIT) do {                                          \
    const uint16_t* g_ = ((ISB) ? Bg : Ag) +                               \
        (size_t)((UNIT) * ((ISB) ? 32 : 64)) * IN_F + (size_t)(Tt) * BK;   \
    uint16_t* l_ = ldsb + ((Tt) & 1) * 32768 + (ISB) * 16384 +             \
                   (UNIT) * 8192 + t * 8;                                  \
    async_cp16(g_, l_);                                                    \
    async_cp16(g_ + (size_t)128 * IN_F, l_ + 4096);                        \
} while (0)

// one tile. BUF=T&1, NB=BUF^1 (literals). VNa..VNd = ENTRY vmcnt literals.
// L2 = P2's lgkm count (8 steady, 0 for last tile).
#define TILE_BODY(T, BUF, NB, DOSTAGE, DONEXT, VNa, VNb, VNc, VNd, L2)     \
    {                                                                      \
        /* P0 */                                                           \
        RD_B(B1f, pB##BUF##k0, pB##BUF##k1, 8192);                         \
        ENTRY(VNa);                                                        \
        LGKM(4);                                                           \
        MFMA_Q(A0f, B0f, 0, 0);                                            \
        EXITB;                                                             \
        /* P1: UA0/VB0 of buf safe (their readers forced at P0.LGKM(4)) */ \
        RD_A(A1f, pA##BUF##k0, pA##BUF##k1, 8192);                         \
        if (DOSTAGE) { STAGE((T) + 2, 0, 0); STAGE((T) + 2, 1, 0); }       \
        ENTRY(VNb);                                                        \
        LGKM(8);                                                           \
        MFMA_Q(A0f, B1f, 0, 2);                                            \
        EXITB;                                                             \
        /* P2: VB1 safe (B1f forced at P1.LGKM(8)) */                      \
        if (DONEXT) RD_A(A0f, pA##NB##k0, pA##NB##k1, 0);                  \
        if (DOSTAGE) STAGE((T) + 2, 1, 1);                                 \
        ENTRY(VNc);                                                        \
        LGKM(L2);                                                          \
        MFMA_Q(A1f, B1f, 4, 2);                                            \
        EXITB;                                                             \
        /* P3: UA1 safe (A1f forced at P2.LGKM) */                         \
        if (DOSTAGE) STAGE((T) + 2, 0, 1);                                 \
        ENTRY(VNd);                                                        \
        LGKM(8);                                                           \
        MFMA_Q(A1f, B0f, 4, 0);                                            \
        if (DONEXT) RD_B(B0f, pB##NB##k0, pB##NB##k1, 0);                  \
        EXITB;                                                             \
    }

// ---------------------------------------------------------------------------
// Prep (one launch): blocks [0,12288) dequant packed int4 -> bf16 W;
// blocks [12288,24576) convert x fp32 -> bf16.
// ---------------------------------------------------------------------------
__global__ __launch_bounds__(256) void prep(const int* __restrict__ packed,
                                            const float* __restrict__ scales,
                                            const float* __restrict__ x,
                                            uint16_t* __restrict__ W,
                                            uint16_t* __restrict__ xb) {
    if (blockIdx.x < 12288) {
        const int t   = blockIdx.x * 256 + threadIdx.x;
        const int idx = t * 4;
        const int row  = idx / (IN_F / 2);
        const int pcol = idx - row * (IN_F / 2);
        const int grp  = pcol >> 6;
        const float s  = scales[row * (IN_F / GROUP) + grp];

        const int4 p = *(const int4*)(packed + idx);
        int vals[4] = {p.x, p.y, p.z, p.w};
        uint32_t w[4];
#pragma unroll
        for (int i = 0; i < 4; ++i) {
            int b  = vals[i] & 255;
            int lo = b & 15;        lo = (lo >= 8) ? lo - 16 : lo;
            int hi = (b >> 4) & 15; hi = (hi >= 8) ? hi - 16 : hi;
            uint32_t e = f2bf((float)lo * s);
            uint32_t o = f2bf((float)hi * s);
            w[i] = e | (o << 16);
        }
        uint4 res = {w[0], w[1], w[2], w[3]};
        *(uint4*)(W + (size_t)idx * 2) = res;
    } else {
        const size_t idx = ((size_t)(blockIdx.x - 12288) * 256 + threadIdx.x) * 8;
        const float4 a = *(const float4*)(x + idx);
        const float4 b = *(const float4*)(x + idx + 4);
        uint32_t w0 = f2bf(a.x) | (f2bf(a.y) << 16);
        uint32_t w1 = f2bf(a.z) | (f2bf(a.w) << 16);
        uint32_t w2 = f2bf(b.x) | (f2bf(b.y) << 16);
        uint32_t w3 = f2bf(b.z) | (f2bf(b.w) << 16);
        uint4 res = {w0, w1, w2, w3};
        *(uint4*)(xb + idx) = res;
    }
}

// ---------------------------------------------------------------------------
// GEMM: C[M,N] = A[M,K] * B[N,K]^T + bias  (bf16 in, fp32 out)
// ---------------------------------------------------------------------------
__global__ __launch_bounds__(512, 2) void gemm_bt(const uint16_t* __restrict__ A,
                                                  const uint16_t* __restrict__ B,
                                                  const float* __restrict__ bias,
                                                  float* __restrict__ C) {
    constexpr int K = IN_F;
    constexpr int N = OUT_F;

    // [buf][0=A,1=B][unit][listrow*64 + slot*8]; slot s of listrow lr holds
    // global chunk s^(lr&7). 2*32768*2B = 128 KiB.
    __shared__ __align__(16) uint16_t lds[2][2][BM * BK];
    uint16_t* ldsb = &lds[0][0][0];

    const int t    = threadIdx.x;
    const int lane = t & 63;
    const int wave = t >> 6;

    // XCD-aware bijective swizzle (1024 wgs, 128 consecutive per XCD)
    const int wg  = blockIdx.x;
    const int swz = (wg & 7) * 128 + (wg >> 3);
    const int bx  = swz & 31;
    const int by  = swz >> 5;

    const int wm = (wave >> 2) * 128;  // 0 / 128
    const int wn = (wave & 3) * 64;    // 0/64/128/192

    const int fr = lane & 15;
    const int qq = lane >> 4;
    const int fx = fr & 7;
    const int c0 = qq ^ fx;            // ks=0 chunk, per-lane

    // staging bases
    const int r0 = t >> 3;                 // 0..63
    const int rB = r0 + (r0 & 32);         // B row base (bit5 spread)
    const int sx = (t & 7) ^ (r0 & 7);     // swizzled global 16B chunk
    const uint16_t* Ag = A + (size_t)(by * 256 + r0) * K + sx * 8;
    const uint16_t* Bg = B + (size_t)(bx * 256 + rB) * K + sx * 8;

    // lane-base LDS pointers (digit = buffer). Unit offsets via +8192 imm.
    // A listrow = (wm>>1) + i*16 + fr (+64 per unit-half via imm)
    // B listrow = (wn>>6)*32 + j*16 + fr
    const uint16_t* pA0k0 = ldsb + ((wm >> 1) + fr) * 64 + c0 * 8;
    const uint16_t* pA0k1 = ldsb + ((wm >> 1) + fr) * 64 + (c0 ^ 4) * 8;
    const uint16_t* pA1k0 = pA0k0 + 32768;
    const uint16_t* pA1k1 = pA0k1 + 32768;
    const uint16_t* pB0k0 = ldsb + 16384 + ((wn >> 6) * 32 + fr) * 64 + c0 * 8;
    const uint16_t* pB0k1 = ldsb + 16384 + ((wn >> 6) * 32 + fr) * 64 + (c0 ^ 4) * 8;
    const uint16_t* pB1k0 = pB0k0 + 32768;
    const uint16_t* pB1k1 = pB0k1 + 32768;

    f32x4 acc[8][4] = {};
    bf16x8 A0f[4][2], A1f[4][2], B0f[2][2], B1f[2][2];

    // prologue: tiles 0,1 in steady issue order (UA0, VB0, VB1, UA1)
    STAGE(0, 0, 0); STAGE(0, 1, 0); STAGE(0, 1, 1); STAGE(0, 0, 1);
    STAGE(1, 0, 0); STAGE(1, 1, 0); STAGE(1, 1, 1); STAGE(1, 0, 1);
    asm volatile("s_waitcnt vmcnt(8)" ::: "memory");   // tile0 resident
    __builtin_amdgcn_s_barrier();
    asm volatile("" ::: "memory");
    RD_B(B0f, pB0k0, pB0k1, 0);    // VB0(0)
    RD_A(A0f, pA0k0, pA0k1, 0);    // UA0(0)

    for (int tp = 0; tp < NT - 2; tp += 2) {
        TILE_BODY(tp,     0, 1, true, true, 8, 8, 8, 8, 8);
        TILE_BODY(tp + 1, 1, 0, true, true, 8, 8, 8, 8, 8);
    }
    TILE_BODY(NT - 2, 0, 1, false, true,  8, 4, 2, 0, 8);
    TILE_BODY(NT - 1, 1, 0, false, false, 0, 0, 0, 0, 0);

    // --- epilogue: C/D layout col=lane&15, row=(lane>>4)*4+reg ---
    const int cr = (lane >> 4) * 4;
    const int cc = lane & 15;
#pragma unroll
    for (int j = 0; j < 4; ++j) {
        const int col = bx * BN + wn + j * 16 + cc;
        const float bv = bias[col];
#pragma unroll
        for (int i = 0; i < 8; ++i) {
            const size_t base = (size_t)(by * BM + wm + i * 16 + cr) * N + col;
#pragma unroll
            for (int r = 0; r < 4; ++r)
                C[base + (size_t)r * N] = acc[i][j][r] + bv;
        }
    }
}

extern "C" void kernel_launch(void* const* d_in, const int* in_sizes, int n_in,
                              void* d_out, int out_size, void* d_ws, size_t ws_size,
                              hipStream_t stream) {
    const float* x      = (const float*)d_in[0];   // [8192, 3072] fp32
    const int*   packed = (const int*)d_in[1];     // [8192, 1536] int32 (byte vals)
    const float* scales = (const float*)d_in[2];   // [8192, 24] fp32
    const float* bias   = (const float*)d_in[3];   // [8192] fp32
    float*       out    = (float*)d_out;           // [8192, 8192] fp32

    uint16_t* W  = (uint16_t*)d_ws;                                     // 50.3 MB bf16
    uint16_t* Xb = (uint16_t*)((char*)d_ws + (size_t)OUT_F * IN_F * 2); // 50.3 MB bf16

    prep<<<24576, 256, 0, stream>>>(packed, scales, x, W, Xb);

    gemm_bt<<<dim3(1024), 512, 0, stream>>>(Xb, W, bias, out);
}

// Round 7
// 710.853 us; speedup vs baseline: 2.9292x; 1.0384x over previous
//
#include <hip/hip_runtime.h>
#include <stdint.h>

#define TOKENS 8192
#define IN_F   3072
#define OUT_F  8192
#define GROUP  128

// GEMM: 256x256 tile, BK=64, 8 waves (2M x 4N), 512 threads.
// R7 = R6's proven-correct geometry + ledger, with the over-fencing removed
// (m141 lesson: sched_barrier/memory-clobber pinning defeats the compiler's
// own fine-grained scheduling, which is what produces LDS/MFMA overlap).
// - waitcnt asm: NO clobber, NO sched_barrier -> advisory floor; compiler's
//   own per-use lgkmcnt waits carry ds_read->MFMA RAW correctness.
// - vmcnt(8) only at P1 and P3 (pre-barrier): carries global_load_lds
//   residency + WAR. Ledger (units: per tile, issue order UA0,VB0 @P1;
//   VB1 @P2; UA1 @P3; 2 loads each):
//     P1(T) vmcnt(8): newest 8 = {UA0/VB0(T+2), VB1(T+1), UA1(T+1)} ->
//       forces UA0/VB0(T+1) (read at P2(T)/P3(T)-end) and older.
//     P3(T) vmcnt(8): newest 8 = {UA0/VB0(T+2), VB1(T+2), UA1(T+2)} ->
//       forces VB1(T+1) (read P0(T+1)) and UA1(T+1) (read P1(T+1)).
//   Every forced unit issued >=4 phases (~1 tile) earlier; never drains.
// - Loads cannot cross barriers (compiler fence at BAR only); any legal
//   reordering of stages across a waitcnt makes the wait deeper (safe).
// Units (congruent with register sets for ALL waves):
//   UA0 = rows {0..63}u{128..191}, UA1 = {64..127}u{192..255}
//   VB0 = rows bit5==0,            VB1 = rows bit5==1
// Reads: P0 B1f[4], P1 A1f[8], P2 A0f(next)[8], P3end B0f(next)[4].
// MFMA:  P0 A0xB0,  P1 A0xB1,  P2 A1xB1,       P3 A1xB0.
#define BM 256
#define BN 256
#define BK 64
#define NT (IN_F / BK)   // 48 K-tiles

typedef __bf16 bf16x8 __attribute__((ext_vector_type(8)));
typedef float  f32x4  __attribute__((ext_vector_type(4)));

__device__ __forceinline__ uint32_t f2bf(float f) {
    union { float f; uint32_t u; } v; v.f = f;
    uint32_t u = v.u;
    return (u + 0x7fffu + ((u >> 16) & 1u)) >> 16;
}

__device__ __forceinline__ void async_cp16(const uint16_t* g, uint16_t* l) {
    __builtin_amdgcn_global_load_lds(
        (const __attribute__((address_space(1))) void*)g,
        (__attribute__((address_space(3))) void*)l,
        16, 0, 0);
}

// barrier with compiler memory fence (loads/stages may not cross phases)
#define BAR()                                                              \
    asm volatile("" ::: "memory");                                         \
    __builtin_amdgcn_s_barrier();                                          \
    asm volatile("" ::: "memory");

// advisory counted waits: NO clobber, NO sched_barrier (compiler schedules)
#define WAITLGKM(N) asm volatile("s_waitcnt lgkmcnt(" #N ")");
#define WAITVM(N)   asm volatile("s_waitcnt vmcnt(" #N ")");

// one C-quadrant: 16 MFMA (4x2 frags x 2 ks)
#define MFMA_Q(Aset, Bset, ro, co)                                         \
    __builtin_amdgcn_s_setprio(1);                                         \
    _Pragma("unroll") for (int ks = 0; ks < 2; ++ks)                       \
    _Pragma("unroll") for (int i = 0; i < 4; ++i)                          \
    _Pragma("unroll") for (int j = 0; j < 2; ++j)                          \
        acc[(ro) + i][(co) + j] = __builtin_amdgcn_mfma_f32_16x16x32_bf16( \
            Aset[i][ks], Bset[j][ks], acc[(ro) + i][(co) + j], 0, 0, 0);   \
    __builtin_amdgcn_s_setprio(0);

// ds_read a 4x2 A-set / 2x2 B-set from lane-base pointers + immediates
#define RD_A(dst, PK0, PK1, HIMM)                                          \
    _Pragma("unroll") for (int i = 0; i < 4; ++i) {                        \
        dst[i][0] = *(const bf16x8*)((PK0) + (HIMM) + i * 1024);           \
        dst[i][1] = *(const bf16x8*)((PK1) + (HIMM) + i * 1024);           \
    }
#define RD_B(dst, PK0, PK1, HIMM)                                          \
    _Pragma("unroll") for (int j = 0; j < 2; ++j) {                        \
        dst[j][0] = *(const bf16x8*)((PK0) + (HIMM) + j * 1024);           \
        dst[j][1] = *(const bf16x8*)((PK1) + (HIMM) + j * 1024);           \
    }

// stage one unit (2 x global_load_lds_dwordx4 per thread, p stride 128 rows)
#define STAGE(Tt, ISB, UNIT) do {                                          \
    const uint16_t* g_ = ((ISB) ? Bg : Ag) +                               \
        (size_t)((UNIT) * ((ISB) ? 32 : 64)) * IN_F + (size_t)(Tt) * BK;   \
    uint16_t* l_ = ldsb + ((Tt) & 1) * 32768 + (ISB) * 16384 +             \
                   (UNIT) * 8192 + t * 8;                                  \
    async_cp16(g_, l_);                                                    \
    async_cp16(g_ + (size_t)128 * IN_F, l_ + 4096);                        \
} while (0)

// one tile. BUF=T&1, NB=BUF^1 (literals).
#define TILE_BODY(T, BUF, NB, DOSTAGE, DONEXT)                             \
    {                                                                      \
        /* P0 */                                                           \
        RD_B(B1f, pB##BUF##k0, pB##BUF##k1, 8192);                         \
        BAR();                                                             \
        WAITLGKM(4);                                                       \
        MFMA_Q(A0f, B0f, 0, 0);                                            \
        BAR();                                                             \
        /* P1: UA0/VB0(T) readers forced (P0 lgkm + barrier) */            \
        RD_A(A1f, pA##BUF##k0, pA##BUF##k1, 8192);                         \
        if (DOSTAGE) { STAGE((T) + 2, 0, 0); STAGE((T) + 2, 1, 0); }       \
        WAITVM(8);                                                         \
        BAR();                                                             \
        WAITLGKM(8);                                                       \
        MFMA_Q(A0f, B1f, 0, 2);                                            \
        BAR();                                                             \
        /* P2: VB1(T) readers forced (P1 lgkm + barrier) */                \
        if (DONEXT) RD_A(A0f, pA##NB##k0, pA##NB##k1, 0);                  \
        if (DOSTAGE) STAGE((T) + 2, 1, 1);                                 \
        BAR();                                                             \
        WAITLGKM(8);                                                       \
        MFMA_Q(A1f, B1f, 4, 2);                                            \
        BAR();                                                             \
        /* P3: UA1(T) readers forced (P2 lgkm + barrier) */                \
        if (DOSTAGE) STAGE((T) + 2, 0, 1);                                 \
        WAITVM(8);                                                         \
        BAR();                                                             \
        WAITLGKM(8);                                                       \
        MFMA_Q(A1f, B0f, 4, 0);                                            \
        if (DONEXT) RD_B(B0f, pB##NB##k0, pB##NB##k1, 0);                  \
        BAR();                                                             \
    }

// ---------------------------------------------------------------------------
// Prep (one launch): blocks [0,12288) dequant packed int4 -> bf16 W;
// blocks [12288,24576) convert x fp32 -> bf16.
// ---------------------------------------------------------------------------
__global__ __launch_bounds__(256) void prep(const int* __restrict__ packed,
                                            const float* __restrict__ scales,
                                            const float* __restrict__ x,
                                            uint16_t* __restrict__ W,
                                            uint16_t* __restrict__ xb) {
    if (blockIdx.x < 12288) {
        const int t   = blockIdx.x * 256 + threadIdx.x;
        const int idx = t * 4;
        const int row  = idx / (IN_F / 2);
        const int pcol = idx - row * (IN_F / 2);
        const int grp  = pcol >> 6;
        const float s  = scales[row * (IN_F / GROUP) + grp];

        const int4 p = *(const int4*)(packed + idx);
        int vals[4] = {p.x, p.y, p.z, p.w};
        uint32_t w[4];
#pragma unroll
        for (int i = 0; i < 4; ++i) {
            int b  = vals[i] & 255;
            int lo = b & 15;        lo = (lo >= 8) ? lo - 16 : lo;
            int hi = (b >> 4) & 15; hi = (hi >= 8) ? hi - 16 : hi;
            uint32_t e = f2bf((float)lo * s);
            uint32_t o = f2bf((float)hi * s);
            w[i] = e | (o << 16);
        }
        uint4 res = {w[0], w[1], w[2], w[3]};
        *(uint4*)(W + (size_t)idx * 2) = res;
    } else {
        const size_t idx = ((size_t)(blockIdx.x - 12288) * 256 + threadIdx.x) * 8;
        const float4 a = *(const float4*)(x + idx);
        const float4 b = *(const float4*)(x + idx + 4);
        uint32_t w0 = f2bf(a.x) | (f2bf(a.y) << 16);
        uint32_t w1 = f2bf(a.z) | (f2bf(a.w) << 16);
        uint32_t w2 = f2bf(b.x) | (f2bf(b.y) << 16);
        uint32_t w3 = f2bf(b.z) | (f2bf(b.w) << 16);
        uint4 res = {w0, w1, w2, w3};
        *(uint4*)(xb + idx) = res;
    }
}

// ---------------------------------------------------------------------------
// GEMM: C[M,N] = A[M,K] * B[N,K]^T + bias  (bf16 in, fp32 out)
// ---------------------------------------------------------------------------
__global__ __launch_bounds__(512, 2) void gemm_bt(const uint16_t* __restrict__ A,
                                                  const uint16_t* __restrict__ B,
                                                  const float* __restrict__ bias,
                                                  float* __restrict__ C) {
    constexpr int K = IN_F;
    constexpr int N = OUT_F;

    // [buf][0=A,1=B][unit][listrow*64 + slot*8]; slot s of listrow lr holds
    // global chunk s^(lr&7). 2*32768*2B = 128 KiB.
    __shared__ __align__(16) uint16_t lds[2][2][BM * BK];
    uint16_t* ldsb = &lds[0][0][0];

    const int t    = threadIdx.x;
    const int lane = t & 63;
    const int wave = t >> 6;

    // XCD-aware bijective swizzle (1024 wgs, 128 consecutive per XCD)
    const int wg  = blockIdx.x;
    const int swz = (wg & 7) * 128 + (wg >> 3);
    const int bx  = swz & 31;
    const int by  = swz >> 5;

    const int wm = (wave >> 2) * 128;  // 0 / 128
    const int wn = (wave & 3) * 64;    // 0/64/128/192

    const int fr = lane & 15;
    const int qq = lane >> 4;
    const int fx = fr & 7;
    const int c0 = qq ^ fx;            // ks=0 chunk, per-lane

    // staging bases
    const int r0 = t >> 3;                 // 0..63
    const int rB = r0 + (r0 & 32);         // B row base (bit5 spread)
    const int sx = (t & 7) ^ (r0 & 7);     // swizzled global 16B chunk
    const uint16_t* Ag = A + (size_t)(by * 256 + r0) * K + sx * 8;
    const uint16_t* Bg = B + (size_t)(bx * 256 + rB) * K + sx * 8;

    // lane-base LDS pointers (digit = buffer). Unit offsets via +8192 imm.
    const uint16_t* pA0k0 = ldsb + ((wm >> 1) + fr) * 64 + c0 * 8;
    const uint16_t* pA0k1 = ldsb + ((wm >> 1) + fr) * 64 + (c0 ^ 4) * 8;
    const uint16_t* pA1k0 = pA0k0 + 32768;
    const uint16_t* pA1k1 = pA0k1 + 32768;
    const uint16_t* pB0k0 = ldsb + 16384 + ((wn >> 6) * 32 + fr) * 64 + c0 * 8;
    const uint16_t* pB0k1 = ldsb + 16384 + ((wn >> 6) * 32 + fr) * 64 + (c0 ^ 4) * 8;
    const uint16_t* pB1k0 = pB0k0 + 32768;
    const uint16_t* pB1k1 = pB0k1 + 32768;

    f32x4 acc[8][4] = {};
    bf16x8 A0f[4][2], A1f[4][2], B0f[2][2], B1f[2][2];

    // prologue: tiles 0,1 in steady issue order (UA0, VB0, VB1, UA1)
    STAGE(0, 0, 0); STAGE(0, 1, 0); STAGE(0, 1, 1); STAGE(0, 0, 1);
    STAGE(1, 0, 0); STAGE(1, 1, 0); STAGE(1, 1, 1); STAGE(1, 0, 1);
    WAITVM(8);                         // tile0 resident; tile1 in flight
    BAR();
    RD_B(B0f, pB0k0, pB0k1, 0);        // VB0(0)
    RD_A(A0f, pA0k0, pA0k1, 0);        // UA0(0)

    for (int tp = 0; tp < NT - 2; tp += 2) {
        TILE_BODY(tp,     0, 1, true, true);
        TILE_BODY(tp + 1, 1, 0, true, true);
    }
    TILE_BODY(NT - 2, 0, 1, false, true);
    TILE_BODY(NT - 1, 1, 0, false, false);

    // --- epilogue: C/D layout col=lane&15, row=(lane>>4)*4+reg ---
    // nontemporal: C is write-once streaming; keep it out of L2/L3 so A/B
    // panels stay resident (FETCH_SIZE 833 MB >> ~100 MB working set).
    const int cr = (lane >> 4) * 4;
    const int cc = lane & 15;
#pragma unroll
    for (int j = 0; j < 4; ++j) {
        const int col = bx * BN + wn + j * 16 + cc;
        const float bv = bias[col];
#pragma unroll
        for (int i = 0; i < 8; ++i) {
            const size_t base = (size_t)(by * BM + wm + i * 16 + cr) * N + col;
#pragma unroll
            for (int r = 0; r < 4; ++r)
                __builtin_nontemporal_store(acc[i][j][r] + bv,
                                            &C[base + (size_t)r * N]);
        }
    }
}

extern "C" void kernel_launch(void* const* d_in, const int* in_sizes, int n_in,
                              void* d_out, int out_size, void* d_ws, size_t ws_size,
                              hipStream_t stream) {
    const float* x      = (const float*)d_in[0];   // [8192, 3072] fp32
    const int*   packed = (const int*)d_in[1];     // [8192, 1536] int32 (byte vals)
    const float* scales = (const float*)d_in[2];   // [8192, 24] fp32
    const float* bias   = (const float*)d_in[3];   // [8192] fp32
    float*       out    = (float*)d_out;           // [8192, 8192] fp32

    uint16_t* W  = (uint16_t*)d_ws;                                     // 50.3 MB bf16
    uint16_t* Xb = (uint16_t*)((char*)d_ws + (size_t)OUT_F * IN_F * 2); // 50.3 MB bf16

    prep<<<24576, 256, 0, stream>>>(packed, scales, x, W, Xb);

    gemm_bt<<<dim3(1024), 512, 0, stream>>>(Xb, W, bias, out);
}